// Round 15
// baseline (924.705 us; speedup 1.0000x reference)
//
#include <hip/hip_runtime.h>
#include <math.h>

// CurvatureLoss via x-sorted window KNN with block-uniform loops.
// B=2, N=8192, [B,N,3] fp32. sort: each set {tgt, src, warped} by x into 256
// buckets (monotone clamped). knn per block: 16 queries x 16 lanes; the 512
// sorted points around the block's queries are staged ONCE in LDS.
//   phase A: per-lane float top-4 over the CENTRAL 256 of the window (uniform
//     16 iters); leader merges pooled 64 -> T = K-th smallest (valid upper
//     bound on the true K-th distance: order statistic of real candidates).
//   phase B1: filter the full 512-pt LDS window with d<=T; B2: block-union
//     x-slivers outside the window (global reads, identical addrs across
//     query groups). Buffer ALL d<=T points exactly once -> >=K guaranteed
//     (the K pooled-smallest are window points with d<=T).
//   overflow (hits>CAP, rare): per-lane lex insert-RESCAN of window+slivers
//     (no cross-lane handoff -> legal in divergent branch). Correctness never
//     depends on CAP.
//   final: exact lex (d, orig_idx) top-K == jax.lax.top_k (unique keys =>
//     deterministic despite atomic scatter order). Epilogues byte-identical
//     to the absmax-0.0 rounds.

constexpr int SBLK  = 256;
constexpr int BLOCK = 256;
constexpr int NB1   = 256;           // 1D x-buckets
constexpr float XLO = -8.0f, XHI = 8.0f;
constexpr float BKS = NB1 / (XHI - XLO);
constexpr int WPTS  = 512;           // LDS window (scanned in B1)
constexpr int AWIN  = 256;           // central T-sample sub-window (phase A)
constexpr float RADIUS2 = 2.5f;

__device__ __forceinline__ float sq3(float x, float y, float z) {
    return fmaf(x, x, fmaf(y, y, z * z));
}
__device__ __forceinline__ bool lex_less(float d1, int i1, float d2, int i2) {
    return (d1 < d2) || (d1 == d2 && i1 < i2);
}
__device__ __forceinline__ int bkt1(float v) {   // monotone with clamp
    int k = (int)((v - XLO) * BKS);
    return k < 0 ? 0 : (k > NB1 - 1 ? NB1 - 1 : k);
}

// x-bucket sort one (set,b): set 0=tgt, 1=src, 2=warped. grid = 6 blocks.
__global__ __launch_bounds__(SBLK)
void sort_kernel(const float* __restrict__ src, const float* __restrict__ tgt,
                 const float* __restrict__ flow,
                 float4* __restrict__ xyzw, int* __restrict__ sidx,
                 int* __restrict__ bstart, int N)
{
    const int set = blockIdx.x >> 1;
    const int b   = blockIdx.x & 1;
    const size_t pbase = (size_t)b * N * 3;
    const float* P = (set == 0) ? tgt : src;
    const bool addF = (set == 2);
    float4* oxy = xyzw + (size_t)blockIdx.x * N;
    int*    osx = sidx + (size_t)blockIdx.x * N;
    int*    obs = bstart + (size_t)blockIdx.x * (NB1 + 1);

    __shared__ int hist[NB1];
    __shared__ int scan[NB1 + 1];
    const int t = threadIdx.x;   // SBLK == NB1: thread t owns bucket t

    hist[t] = 0;
    __syncthreads();
    for (int i = t; i < N; i += SBLK) {
        float x = P[pbase + (size_t)i * 3];
        if (addF) x += flow[pbase + (size_t)i * 3];
        atomicAdd(&hist[bkt1(x)], 1);
    }
    __syncthreads();
    if (t == 0) {
        int run = 0;
        for (int k = 0; k < NB1; ++k) { scan[k] = run; run += hist[k]; }
        scan[NB1] = run;
    }
    __syncthreads();
    obs[t] = scan[t];
    if (t == 0) obs[NB1] = scan[NB1];
    hist[t] = scan[t];               // scatter cursor
    __syncthreads();
    for (int i = t; i < N; i += SBLK) {
        size_t o = pbase + (size_t)i * 3;
        float x = P[o], y = P[o + 1], z = P[o + 2];
        if (addF) { x += flow[o]; y += flow[o + 1]; z += flow[o + 2]; }
        int pos = atomicAdd(&hist[bkt1(x)], 1);
        oxy[pos] = make_float4(x, y, z, sq3(x, y, z));
        osx[pos] = i;
    }
}

// KIND 0: self-KNN curvature (mode 0: tgt->curv2=outA; mode 1: src, gather warped->moved=outB)
// KIND 1: warped->tgt KNN, interp curv2, subtract moved, loss -> outA
template <int K, int CPQ, int KIND, int CAP>
__global__ __launch_bounds__(BLOCK)
void knn_kernel(const float* __restrict__ src, const float* __restrict__ tgt,
                const float* __restrict__ flow,
                const float4* __restrict__ ws_xyzw, const int* __restrict__ ws_sidx,
                const int* __restrict__ ws_bs,
                const float* __restrict__ curv2, const float* __restrict__ moved,
                float* __restrict__ outA, float* __restrict__ outB,
                int N, float invB)
{
    constexpr int QPB = BLOCK / CPQ;   // 16 queries/block; 16 lanes in ONE wave
    static_assert(CPQ * 4 <= CAP && CPQ * K <= CAP, "CAP too small");
    static_assert(64 % CPQ == 0, "query group must sit inside one wave");
    __shared__ float4 swin[WPTS];
    __shared__ float  pool_d[QPB * CAP];
    __shared__ int    pool_i[QPB * CAP];
    __shared__ int    sbs[NB1 + 1];
    __shared__ float  Tsh[QPB];
    __shared__ int    hcnt[QPB];
    __shared__ int    uminS, umaxS;
    __shared__ float  lsum;

    const int tid = threadIdx.x;
    const int ql  = tid / CPQ;
    const int c   = tid % CPQ;
    const int bpb = N / QPB;

    int blk = blockIdx.x;
    int mode = 0;
    if (KIND == 0) { int half = gridDim.x >> 1; mode = (blk >= half); blk -= mode ? half : 0; }
    const int b  = blk / bpb;
    const int q0 = (blk % bpb) * QPB;
    const size_t bbase = (size_t)b * N * 3;

    const int qset = (KIND == 0) ? mode : 2;
    const int rset = (KIND == 0) ? mode : 0;
    const float4* sQ  = ws_xyzw + (size_t)(qset * 2 + b) * N;
    const int*    sQi = ws_sidx + (size_t)(qset * 2 + b) * N;
    const float4* sRf = ws_xyzw + (size_t)(rset * 2 + b) * N;
    const int*    sRi = ws_sidx + (size_t)(rset * 2 + b) * N;
    const int*    bsR = ws_bs   + (size_t)(rset * 2 + b) * (NB1 + 1);

    const int qpos = q0 + ql;
    const float4 q4 = sQ[qpos];
    const int oqi = sQi[qpos];
    const float qx = q4.x, qy = q4.y, qz = q4.z, qq = q4.w;
    const float m2x = -2.0f * qx, m2y = -2.0f * qy, m2z = -2.0f * qz;
    const int qbase = ql * CAP;

    // ---- stage bucket table + window (block-uniform) ----
    for (int k = tid; k <= NB1; k += BLOCK) sbs[k] = bsR[k];

    int wA0;
    if (KIND == 0) {
        wA0 = q0 + QPB / 2 - WPTS / 2;
    } else {
        float xm = sQ[q0 + QPB / 2].x;
        wA0 = bsR[bkt1(xm)] - WPTS / 2;
    }
    wA0 = min(max(wA0, 0), N - WPTS);
    const int wA1 = wA0 + WPTS;

    for (int j = tid; j < WPTS; j += BLOCK) swin[j] = sRf[wA0 + j];
    if (tid == 0) { uminS = wA0; umaxS = wA1; lsum = 0.0f; }
    if (c == 0) hcnt[ql] = 0;
    __syncthreads();

    // ---- phase A: per-lane float top-4 over CENTRAL AWIN points (uniform) ----
    constexpr int AOFF = (WPTS - AWIN) / 2;
    float a0 = INFINITY, a1 = INFINITY, a2 = INFINITY, a3 = INFINITY;
#pragma unroll
    for (int i = 0; i < AWIN / CPQ; ++i) {
        float4 p = swin[AOFF + i * CPQ + c];   // broadcast across query groups
        float d = fmaf(m2x, p.x, fmaf(m2y, p.y, fmaf(m2z, p.z, qq + p.w)));
        if (d < a3) {
            a3 = d; float tt;
            if (a3 < a2) { tt = a2; a2 = a3; a3 = tt; }
            if (a2 < a1) { tt = a1; a1 = a2; a2 = tt; }
            if (a1 < a0) { tt = a0; a0 = a1; a1 = tt; }
        }
    }
    {   // role a1: per-lane sorted top-4
        int o = qbase + c * 4;
        pool_d[o] = a0; pool_d[o + 1] = a1; pool_d[o + 2] = a2; pool_d[o + 3] = a3;
    }
    __syncthreads();

    if (c == 0) {   // T = K-th smallest of pooled CPQ*4 (upper bound, near-tight)
        int pp[CPQ];
#pragma unroll
        for (int cc = 0; cc < CPQ; ++cc) pp[cc] = 0;
        float kth = INFINITY;
#pragma unroll
        for (int k = 0; k < K; ++k) {
            float bdm = INFINITY; int bc = 0;
#pragma unroll
            for (int cc = 0; cc < CPQ; ++cc) {
                float dd = (pp[cc] < 4) ? pool_d[qbase + cc * 4 + pp[cc]] : INFINITY;
                if (dd < bdm) { bdm = dd; bc = cc; }
            }
            kth = bdm;
#pragma unroll
            for (int cc = 0; cc < CPQ; ++cc) pp[cc] += (bc == cc);
        }
        Tsh[ql] = kth;
        float s = sqrtf(kth);
        atomicMin(&uminS, sbs[bkt1(qx - s)]);
        atomicMax(&umaxS, sbs[bkt1(qx + s) + 1]);
    }
    __syncthreads();
    const float T = Tsh[ql];
    const int um = max(uminS, 0), uM = min(umaxS, N);

    // ---- phase B1: filter the full LDS window ----
    for (int i = 0; i < WPTS / CPQ; ++i) {
        const int j = i * CPQ + c;
        float4 p = swin[j];
        float d = fmaf(m2x, p.x, fmaf(m2y, p.y, fmaf(m2z, p.z, qq + p.w)));
        bool hit = d <= T;
        if (__any(hit)) {
            if (hit) {
                int slot = atomicAdd(&hcnt[ql], 1);
                if (slot < CAP) { pool_d[qbase + slot] = d; pool_i[qbase + slot] = sRi[wA0 + j]; }
            }
        }
    }
    // ---- phase B2: block-union slivers outside the window (global) ----
    for (int seg = 0; seg < 2; ++seg) {
        const int s0 = seg ? wA1 : um;
        const int s1 = seg ? uM  : wA0;
        for (int p = s0 + c; p < s1; p += CPQ) {
            float4 pt = sRf[p];
            float d = fmaf(m2x, pt.x, fmaf(m2y, pt.y, fmaf(m2z, pt.z, qq + pt.w)));
            bool hit = d <= T;
            if (__any(hit)) {
                if (hit) {
                    int slot = atomicAdd(&hcnt[ql], 1);
                    if (slot < CAP) { pool_d[qbase + slot] = d; pool_i[qbase + slot] = sRi[p]; }
                }
            }
        }
    }
    __syncthreads();

    // ---- final select: buffer insert, or exact rescan on overflow ----
    const int cnt = min(hcnt[ql], CAP);
    const bool ovf = hcnt[ql] > CAP;
    float nd[K]; int ni[K];
#pragma unroll
    for (int k = 0; k < K; ++k) { nd[k] = INFINITY; ni[k] = 0x7FFFFFFF; }

    if (!ovf) {
        for (int h = c; h < cnt; h += CPQ) {
            float d = pool_d[qbase + h]; int ii = pool_i[qbase + h];
            if (lex_less(d, ii, nd[K - 1], ni[K - 1])) {
                nd[K - 1] = d; ni[K - 1] = ii;
#pragma unroll
                for (int p2 = K - 1; p2 > 0; --p2) {
                    if (lex_less(nd[p2], ni[p2], nd[p2 - 1], ni[p2 - 1])) {
                        float td = nd[p2]; nd[p2] = nd[p2 - 1]; nd[p2 - 1] = td;
                        int ti = ni[p2];  ni[p2] = ni[p2 - 1]; ni[p2 - 1] = ti;
                    }
                }
            }
        }
    } else {
        // exact rescan: window (LDS, read-only) + slivers (global); per-lane
        // lex insert, no cross-lane handoff -> safe in divergent branch
        for (int i = 0; i < WPTS / CPQ; ++i) {
            const int j = i * CPQ + c;
            float4 p = swin[j];
            float d = fmaf(m2x, p.x, fmaf(m2y, p.y, fmaf(m2z, p.z, qq + p.w)));
            int ii = sRi[wA0 + j];
            bool pass = lex_less(d, ii, nd[K - 1], ni[K - 1]);
            if (__any(pass)) {
                if (pass) {
                    nd[K - 1] = d; ni[K - 1] = ii;
#pragma unroll
                    for (int p2 = K - 1; p2 > 0; --p2) {
                        if (lex_less(nd[p2], ni[p2], nd[p2 - 1], ni[p2 - 1])) {
                            float t2 = nd[p2]; nd[p2] = nd[p2 - 1]; nd[p2 - 1] = t2;
                            int ti = ni[p2];  ni[p2] = ni[p2 - 1]; ni[p2 - 1] = ti;
                        }
                    }
                }
            }
        }
        for (int seg = 0; seg < 2; ++seg) {
            const int s0 = seg ? wA1 : um;
            const int s1 = seg ? uM  : wA0;
            for (int p = s0 + c; p < s1; p += CPQ) {
                float4 pt = sRf[p];
                float d = fmaf(m2x, pt.x, fmaf(m2y, pt.y, fmaf(m2z, pt.z, qq + pt.w)));
                int ii = sRi[p];
                bool pass = lex_less(d, ii, nd[K - 1], ni[K - 1]);
                if (__any(pass)) {
                    if (pass) {
                        nd[K - 1] = d; ni[K - 1] = ii;
#pragma unroll
                        for (int p2 = K - 1; p2 > 0; --p2) {
                            if (lex_less(nd[p2], ni[p2], nd[p2 - 1], ni[p2 - 1])) {
                                float t2 = nd[p2]; nd[p2] = nd[p2 - 1]; nd[p2 - 1] = t2;
                                int ti = ni[p2];  ni[p2] = ni[p2 - 1]; ni[p2 - 1] = ti;
                            }
                        }
                    }
                }
            }
        }
    }
    __syncthreads();   // hit buffer consumed
#pragma unroll
    for (int k = 0; k < K; ++k) {   // role a2: per-lane sorted K-lists
        pool_d[qbase + c * K + k] = nd[k];
        pool_i[qbase + c * K + k] = ni[k];
    }
    __syncthreads();

    if (c == 0) {
        int pp[CPQ];
#pragma unroll
        for (int cc = 0; cc < CPQ; ++cc) pp[cc] = 0;
        float fd[K]; int fi[K];
#pragma unroll
        for (int k = 0; k < K; ++k) {
            float bdm = INFINITY; int bim = 0x7FFFFFFF; int bc = -1;
#pragma unroll
            for (int cc = 0; cc < CPQ; ++cc) {
                float dd = pool_d[qbase + cc * K + pp[cc]];
                int   ii = pool_i[qbase + cc * K + pp[cc]];
                if (lex_less(dd, ii, bdm, bim)) { bdm = dd; bim = ii; bc = cc; }
            }
            fd[k] = bdm; fi[k] = bim;
#pragma unroll
            for (int cc = 0; cc < CPQ; ++cc) pp[cc] += (bc == cc);
        }

        if (KIND == 0) {
            const float* rb   = ((mode == 0) ? tgt : src) + bbase;
            const float* addf = flow + bbase;
            float cx = qx, cy = qy, cz = qz;
            float gx = 0.f, gy = 0.f, gz = 0.f;
            if (mode == 1) {   // center = warped[oqi]
                cx += addf[(size_t)oqi * 3 + 0];
                cy += addf[(size_t)oqi * 3 + 1];
                cz += addf[(size_t)oqi * 3 + 2];
            }
#pragma unroll
            for (int k = 0; k < K; ++k) {
                int j = (fd[k] > RADIUS2) ? fi[0] : fi[k];
                float px = rb[(size_t)j * 3 + 0];
                float py = rb[(size_t)j * 3 + 1];
                float pz = rb[(size_t)j * 3 + 2];
                if (mode == 1) {
                    px += addf[(size_t)j * 3 + 0];
                    py += addf[(size_t)j * 3 + 1];
                    pz += addf[(size_t)j * 3 + 2];
                }
                gx += px - cx; gy += py - cy; gz += pz - cz;
            }
            float* outp = (mode == 0) ? outA : outB;
            outp[bbase + (size_t)oqi * 3 + 0] = gx / 9.0f;
            outp[bbase + (size_t)oqi * 3 + 1] = gy / 9.0f;
            outp[bbase + (size_t)oqi * 3 + 2] = gz / 9.0f;
        } else {
            float w[K]; float wsum = 0.f;
#pragma unroll
            for (int k = 0; k < K; ++k) { w[k] = 1.0f / (fd[k] + 1e-8f); wsum += w[k]; }
            float ix = 0.f, iy = 0.f, iz = 0.f;
#pragma unroll
            for (int k = 0; k < K; ++k) {
                int j = (fd[k] > RADIUS2) ? fi[0] : fi[k];
                float wn = w[k] / wsum;
                ix += wn * curv2[bbase + (size_t)j * 3 + 0];
                iy += wn * curv2[bbase + (size_t)j * 3 + 1];
                iz += wn * curv2[bbase + (size_t)j * 3 + 2];
            }
            float dx = ix - moved[bbase + (size_t)oqi * 3 + 0];
            float dy = iy - moved[bbase + (size_t)oqi * 3 + 1];
            float dz = iz - moved[bbase + (size_t)oqi * 3 + 2];
            float sqv = fmaf(dx, dx, fmaf(dy, dy, dz * dz));
            atomicAdd(&lsum, sqv);
        }
    }

    if (KIND == 1) {
        __syncthreads();
        if (tid == 0) atomicAdd(outA, lsum * invB);
    }
}

extern "C" void kernel_launch(void* const* d_in, const int* in_sizes, int n_in,
                              void* d_out, int out_size, void* d_ws, size_t ws_size,
                              hipStream_t stream) {
    const float* src  = (const float*)d_in[0];
    const float* tgt  = (const float*)d_in[1];
    const float* flow = (const float*)d_in[2];
    float* out = (float*)d_out;

    const int B = 2;
    const int N = in_sizes[0] / (B * 3);        // 8192

    float*  curv2  = (float*)d_ws;                         // B*N*3 f32
    float*  moved  = curv2 + (size_t)B * N * 3;            // B*N*3 f32
    float4* xyzw   = (float4*)(moved + (size_t)B * N * 3); // 6*N float4
    int*    sidx   = (int*)(xyzw + (size_t)6 * N);         // 6*N int
    int*    bstart = sidx + (size_t)6 * N;                 // 6*(NB1+1) int

    hipMemsetAsync(d_out, 0, sizeof(float), stream);

    sort_kernel<<<6, SBLK, 0, stream>>>(src, tgt, flow, xyzw, sidx, bstart, N);

    // fused self-KNN curvatures: CPQ=16, QPB=16 -> 2*B*N/16 = 2048 blocks
    knn_kernel<10, 16, 0, 160><<<2 * B * (N / 16), BLOCK, 0, stream>>>(
        src, tgt, flow, xyzw, sidx, bstart, nullptr, nullptr, curv2, moved, N, 0.f);

    // interp + loss: B*N/16 = 1024 blocks
    knn_kernel<5, 16, 1, 96><<<B * (N / 16), BLOCK, 0, stream>>>(
        src, tgt, flow, xyzw, sidx, bstart, curv2, moved, out, nullptr, N, 1.0f / B);
}

// Round 16
// 256.996 us; speedup vs baseline: 3.5981x; 3.5981x over previous
//
#include <hip/hip_runtime.h>
#include <math.h>

// CurvatureLoss via x-sorted window KNN with block-uniform loops (r14 base).
// B=2, N=8192, [B,N,3] fp32. sort: each set {tgt, src, warped} by x into 256
// buckets. knn per block: 16 queries x 16 lanes (each query group = one
// aligned 16-lane segment of a wave); the 1024 sorted points around the
// block's queries are staged ONCE in LDS.
//   phase A: per-lane float top-4 over the full window (uniform 64 iters).
//   T-select: K rounds of 16-lane shfl min-reduce + head-pop over the pooled
//     64 top-4s (register-only; no LDS, no serial leader chain). T = K-th
//     smallest pooled value (float ties joint-pop -> T only gets looser,
//     still a valid upper bound on the true K-th distance).
//   phase B1: filter the full LDS window with d<=T; B2: block-union x-slivers
//     outside the window. Buffer ALL d<=T points exactly once -> >=K hits.
//   overflow (hits>CAP, rare): per-lane lex insert-RESCAN of window+slivers.
//     Correctness never depends on CAP.
//   final: per-lane top-K of buffer slice, then K rounds of 16-lane shfl
//     LEX-min-reduce + pop ((d,idx) unique across lanes -> exactly one pop
//     per round -> exact lex top-K == jax.lax.top_k). Result in registers of
//     every lane; leader runs the epilogue (byte-identical formulas).

constexpr int SBLK  = 256;
constexpr int BLOCK = 256;
constexpr int NB1   = 256;           // 1D x-buckets
constexpr float XLO = -8.0f, XHI = 8.0f;
constexpr float BKS = NB1 / (XHI - XLO);
constexpr int WPTS  = 1024;          // LDS window
constexpr float RADIUS2 = 2.5f;

__device__ __forceinline__ float sq3(float x, float y, float z) {
    return fmaf(x, x, fmaf(y, y, z * z));
}
__device__ __forceinline__ bool lex_less(float d1, int i1, float d2, int i2) {
    return (d1 < d2) || (d1 == d2 && i1 < i2);
}
__device__ __forceinline__ int bkt1(float v) {   // monotone with clamp
    int k = (int)((v - XLO) * BKS);
    return k < 0 ? 0 : (k > NB1 - 1 ? NB1 - 1 : k);
}

// x-bucket sort one (set,b): set 0=tgt, 1=src, 2=warped. grid = 6 blocks.
__global__ __launch_bounds__(SBLK)
void sort_kernel(const float* __restrict__ src, const float* __restrict__ tgt,
                 const float* __restrict__ flow,
                 float4* __restrict__ xyzw, int* __restrict__ sidx,
                 int* __restrict__ bstart, int N)
{
    const int set = blockIdx.x >> 1;
    const int b   = blockIdx.x & 1;
    const size_t pbase = (size_t)b * N * 3;
    const float* P = (set == 0) ? tgt : src;
    const bool addF = (set == 2);
    float4* oxy = xyzw + (size_t)blockIdx.x * N;
    int*    osx = sidx + (size_t)blockIdx.x * N;
    int*    obs = bstart + (size_t)blockIdx.x * (NB1 + 1);

    __shared__ int hist[NB1];
    __shared__ int scan[NB1 + 1];
    const int t = threadIdx.x;   // SBLK == NB1

    hist[t] = 0;
    __syncthreads();
    for (int i = t; i < N; i += SBLK) {
        float x = P[pbase + (size_t)i * 3];
        if (addF) x += flow[pbase + (size_t)i * 3];
        atomicAdd(&hist[bkt1(x)], 1);
    }
    __syncthreads();
    if (t == 0) {
        int run = 0;
        for (int k = 0; k < NB1; ++k) { scan[k] = run; run += hist[k]; }
        scan[NB1] = run;
    }
    __syncthreads();
    obs[t] = scan[t];
    if (t == 0) obs[NB1] = scan[NB1];
    hist[t] = scan[t];               // scatter cursor
    __syncthreads();
    for (int i = t; i < N; i += SBLK) {
        size_t o = pbase + (size_t)i * 3;
        float x = P[o], y = P[o + 1], z = P[o + 2];
        if (addF) { x += flow[o]; y += flow[o + 1]; z += flow[o + 2]; }
        int pos = atomicAdd(&hist[bkt1(x)], 1);
        oxy[pos] = make_float4(x, y, z, sq3(x, y, z));
        osx[pos] = i;
    }
}

// KIND 0: self-KNN curvature (mode 0: tgt->curv2=outA; mode 1: src, gather warped->moved=outB)
// KIND 1: warped->tgt KNN, interp curv2, subtract moved, loss -> outA
template <int K, int CPQ, int KIND, int CAP>
__global__ __launch_bounds__(BLOCK)
void knn_kernel(const float* __restrict__ src, const float* __restrict__ tgt,
                const float* __restrict__ flow,
                const float4* __restrict__ ws_xyzw, const int* __restrict__ ws_sidx,
                const int* __restrict__ ws_bs,
                const float* __restrict__ curv2, const float* __restrict__ moved,
                float* __restrict__ outA, float* __restrict__ outB,
                int N, float invB)
{
    constexpr int QPB = BLOCK / CPQ;   // 16 queries/block
    static_assert(64 % CPQ == 0, "query group must be an aligned wave segment");
    __shared__ float4 swin[WPTS];
    __shared__ float  pool_d[QPB * CAP];
    __shared__ int    pool_i[QPB * CAP];
    __shared__ int    hcnt[QPB];
    __shared__ int    uminS, umaxS;
    __shared__ float  lsum;

    const int tid = threadIdx.x;
    const int ql  = tid / CPQ;
    const int c   = tid % CPQ;
    const int bpb = N / QPB;

    int blk = blockIdx.x;
    int mode = 0;
    if (KIND == 0) { int half = gridDim.x >> 1; mode = (blk >= half); blk -= mode ? half : 0; }
    const int b  = blk / bpb;
    const int q0 = (blk % bpb) * QPB;
    const size_t bbase = (size_t)b * N * 3;

    const int qset = (KIND == 0) ? mode : 2;
    const int rset = (KIND == 0) ? mode : 0;
    const float4* sQ  = ws_xyzw + (size_t)(qset * 2 + b) * N;
    const int*    sQi = ws_sidx + (size_t)(qset * 2 + b) * N;
    const float4* sRf = ws_xyzw + (size_t)(rset * 2 + b) * N;
    const int*    sRi = ws_sidx + (size_t)(rset * 2 + b) * N;
    const int*    bsR = ws_bs   + (size_t)(rset * 2 + b) * (NB1 + 1);

    const int qpos = q0 + ql;
    const float4 q4 = sQ[qpos];
    const int oqi = sQi[qpos];
    const float qx = q4.x, qy = q4.y, qz = q4.z, qq = q4.w;
    const float m2x = -2.0f * qx, m2y = -2.0f * qy, m2z = -2.0f * qz;
    const int qbase = ql * CAP;

    // ---- stage window (block-uniform); init counters ----
    int wA0;
    if (KIND == 0) {
        wA0 = q0 + QPB / 2 - WPTS / 2;
    } else {
        float xm = sQ[q0 + QPB / 2].x;
        wA0 = bsR[bkt1(xm)] - WPTS / 2;
    }
    wA0 = min(max(wA0, 0), N - WPTS);
    const int wA1 = wA0 + WPTS;

    for (int j = tid; j < WPTS; j += BLOCK) swin[j] = sRf[wA0 + j];
    if (tid == 0) { uminS = wA0; umaxS = wA1; lsum = 0.0f; }
    if (c == 0) hcnt[ql] = 0;
    __syncthreads();

    // ---- phase A: per-lane float top-4 over the full window (uniform) ----
    float a0 = INFINITY, a1 = INFINITY, a2 = INFINITY, a3 = INFINITY;
#pragma unroll 8
    for (int i = 0; i < WPTS / CPQ; ++i) {
        float4 p = swin[i * CPQ + c];   // broadcast across query groups
        float d = fmaf(m2x, p.x, fmaf(m2y, p.y, fmaf(m2z, p.z, qq + p.w)));
        if (d < a3) {
            a3 = d; float tt;
            if (a3 < a2) { tt = a2; a2 = a3; a3 = tt; }
            if (a2 < a1) { tt = a1; a1 = a2; a2 = tt; }
            if (a1 < a0) { tt = a0; a0 = a1; a1 = tt; }
        }
    }

    // ---- T-select: K rounds of grouped min-reduce + head-pop (registers) ----
    float T;
    {
        float head = a0; int pp = 0;
        float kth = INFINITY;
#pragma unroll
        for (int k = 0; k < K; ++k) {
            float m = head;
#pragma unroll
            for (int s = 1; s < CPQ; s <<= 1) m = fminf(m, __shfl_xor(m, s, CPQ));
            kth = m;
            if (head <= m) {   // head == m (m is group min incl. head) -> pop
                ++pp;
                head = (pp == 1) ? a1 : (pp == 2) ? a2 : (pp == 3) ? a3 : INFINITY;
            }
        }
        T = kth;
    }
    if (c == 0) {   // per-query sliver union (global bucket table, L2-hot)
        float s = sqrtf(T);
        atomicMin(&uminS, bsR[bkt1(qx - s)]);
        atomicMax(&umaxS, bsR[bkt1(qx + s) + 1]);
    }

    // ---- phase B1: filter the full LDS window ----
    for (int i = 0; i < WPTS / CPQ; ++i) {
        const int j = i * CPQ + c;
        float4 p = swin[j];
        float d = fmaf(m2x, p.x, fmaf(m2y, p.y, fmaf(m2z, p.z, qq + p.w)));
        bool hit = d <= T;
        if (__any(hit)) {
            if (hit) {
                int slot = atomicAdd(&hcnt[ql], 1);
                if (slot < CAP) { pool_d[qbase + slot] = d; pool_i[qbase + slot] = sRi[wA0 + j]; }
            }
        }
    }
    __syncthreads();   // umin/umax + B1 hits visible
    const int um = max(uminS, 0), uM = min(umaxS, N);

    // ---- phase B2: block-union slivers outside the window (global) ----
    for (int seg = 0; seg < 2; ++seg) {
        const int s0 = seg ? wA1 : um;
        const int s1 = seg ? uM  : wA0;
        for (int p = s0 + c; p < s1; p += CPQ) {
            float4 pt = sRf[p];
            float d = fmaf(m2x, pt.x, fmaf(m2y, pt.y, fmaf(m2z, pt.z, qq + pt.w)));
            bool hit = d <= T;
            if (__any(hit)) {
                if (hit) {
                    int slot = atomicAdd(&hcnt[ql], 1);
                    if (slot < CAP) { pool_d[qbase + slot] = d; pool_i[qbase + slot] = sRi[p]; }
                }
            }
        }
    }
    __syncthreads();   // all hits visible

    // ---- per-lane top-K: buffer slice insert, or exact rescan on overflow ----
    const int cnt = min(hcnt[ql], CAP);
    const bool ovf = hcnt[ql] > CAP;
    float nd[K]; int ni[K];
#pragma unroll
    for (int k = 0; k < K; ++k) { nd[k] = INFINITY; ni[k] = 0x7FFFFFFF; }

    if (!ovf) {
        for (int h = c; h < cnt; h += CPQ) {
            float d = pool_d[qbase + h]; int ii = pool_i[qbase + h];
            if (lex_less(d, ii, nd[K - 1], ni[K - 1])) {
                nd[K - 1] = d; ni[K - 1] = ii;
#pragma unroll
                for (int p2 = K - 1; p2 > 0; --p2) {
                    if (lex_less(nd[p2], ni[p2], nd[p2 - 1], ni[p2 - 1])) {
                        float td = nd[p2]; nd[p2] = nd[p2 - 1]; nd[p2 - 1] = td;
                        int ti = ni[p2];  ni[p2] = ni[p2 - 1]; ni[p2 - 1] = ti;
                    }
                }
            }
        }
    } else {
        // exact rescan: window (LDS, intact) + slivers (global); per-lane only
        for (int i = 0; i < WPTS / CPQ; ++i) {
            const int j = i * CPQ + c;
            float4 p = swin[j];
            float d = fmaf(m2x, p.x, fmaf(m2y, p.y, fmaf(m2z, p.z, qq + p.w)));
            int ii = sRi[wA0 + j];
            bool pass = lex_less(d, ii, nd[K - 1], ni[K - 1]);
            if (__any(pass)) {
                if (pass) {
                    nd[K - 1] = d; ni[K - 1] = ii;
#pragma unroll
                    for (int p2 = K - 1; p2 > 0; --p2) {
                        if (lex_less(nd[p2], ni[p2], nd[p2 - 1], ni[p2 - 1])) {
                            float t2 = nd[p2]; nd[p2] = nd[p2 - 1]; nd[p2 - 1] = t2;
                            int ti = ni[p2];  ni[p2] = ni[p2 - 1]; ni[p2 - 1] = ti;
                        }
                    }
                }
            }
        }
        for (int seg = 0; seg < 2; ++seg) {
            const int s0 = seg ? wA1 : um;
            const int s1 = seg ? uM  : wA0;
            for (int p = s0 + c; p < s1; p += CPQ) {
                float4 pt = sRf[p];
                float d = fmaf(m2x, pt.x, fmaf(m2y, pt.y, fmaf(m2z, pt.z, qq + pt.w)));
                int ii = sRi[p];
                bool pass = lex_less(d, ii, nd[K - 1], ni[K - 1]);
                if (__any(pass)) {
                    if (pass) {
                        nd[K - 1] = d; ni[K - 1] = ii;
#pragma unroll
                        for (int p2 = K - 1; p2 > 0; --p2) {
                            if (lex_less(nd[p2], ni[p2], nd[p2 - 1], ni[p2 - 1])) {
                                float t2 = nd[p2]; nd[p2] = nd[p2 - 1]; nd[p2 - 1] = t2;
                                int ti = ni[p2];  ni[p2] = ni[p2 - 1]; ni[p2 - 1] = ti;
                            }
                        }
                    }
                }
            }
        }
    }

    // ---- final: K rounds of grouped LEX-min-reduce + pop (registers) ----
    // (d, idx) unique across lanes -> exactly one pop per round -> exact.
    float fd[K]; int fi[K];
    {
        int pp = 0;
        float hd = nd[0]; int hi = ni[0];
#pragma unroll
        for (int k = 0; k < K; ++k) {
            float md = hd; int mi = hi;
#pragma unroll
            for (int s = 1; s < CPQ; s <<= 1) {
                float od = __shfl_xor(md, s, CPQ);
                int   oi = __shfl_xor(mi, s, CPQ);
                if (lex_less(od, oi, md, mi)) { md = od; mi = oi; }
            }
            fd[k] = md; fi[k] = mi;
            if (hd == md && hi == mi) {   // this lane's head won -> pop
                ++pp;
                float sd = INFINITY; int si = 0x7FFFFFFF;
#pragma unroll
                for (int j = 1; j < K; ++j) if (pp == j) { sd = nd[j]; si = ni[j]; }
                hd = sd; hi = si;
            }
        }
    }

    // ---- epilogue (leader lane of each query group) ----
    if (c == 0) {
        if (KIND == 0) {
            const float* rb   = ((mode == 0) ? tgt : src) + bbase;
            const float* addf = flow + bbase;
            float cx = qx, cy = qy, cz = qz;
            float gx = 0.f, gy = 0.f, gz = 0.f;
            if (mode == 1) {   // center = warped[oqi]
                cx += addf[(size_t)oqi * 3 + 0];
                cy += addf[(size_t)oqi * 3 + 1];
                cz += addf[(size_t)oqi * 3 + 2];
            }
#pragma unroll
            for (int k = 0; k < K; ++k) {
                int j = (fd[k] > RADIUS2) ? fi[0] : fi[k];
                float px = rb[(size_t)j * 3 + 0];
                float py = rb[(size_t)j * 3 + 1];
                float pz = rb[(size_t)j * 3 + 2];
                if (mode == 1) {
                    px += addf[(size_t)j * 3 + 0];
                    py += addf[(size_t)j * 3 + 1];
                    pz += addf[(size_t)j * 3 + 2];
                }
                gx += px - cx; gy += py - cy; gz += pz - cz;
            }
            float* outp = (mode == 0) ? outA : outB;
            outp[bbase + (size_t)oqi * 3 + 0] = gx / 9.0f;
            outp[bbase + (size_t)oqi * 3 + 1] = gy / 9.0f;
            outp[bbase + (size_t)oqi * 3 + 2] = gz / 9.0f;
        } else {
            float w[K]; float wsum = 0.f;
#pragma unroll
            for (int k = 0; k < K; ++k) { w[k] = 1.0f / (fd[k] + 1e-8f); wsum += w[k]; }
            float ix = 0.f, iy = 0.f, iz = 0.f;
#pragma unroll
            for (int k = 0; k < K; ++k) {
                int j = (fd[k] > RADIUS2) ? fi[0] : fi[k];
                float wn = w[k] / wsum;
                ix += wn * curv2[bbase + (size_t)j * 3 + 0];
                iy += wn * curv2[bbase + (size_t)j * 3 + 1];
                iz += wn * curv2[bbase + (size_t)j * 3 + 2];
            }
            float dx = ix - moved[bbase + (size_t)oqi * 3 + 0];
            float dy = iy - moved[bbase + (size_t)oqi * 3 + 1];
            float dz = iz - moved[bbase + (size_t)oqi * 3 + 2];
            float sqv = fmaf(dx, dx, fmaf(dy, dy, dz * dz));
            atomicAdd(&lsum, sqv);
        }
    }

    if (KIND == 1) {
        __syncthreads();
        if (tid == 0) atomicAdd(outA, lsum * invB);
    }
}

extern "C" void kernel_launch(void* const* d_in, const int* in_sizes, int n_in,
                              void* d_out, int out_size, void* d_ws, size_t ws_size,
                              hipStream_t stream) {
    const float* src  = (const float*)d_in[0];
    const float* tgt  = (const float*)d_in[1];
    const float* flow = (const float*)d_in[2];
    float* out = (float*)d_out;

    const int B = 2;
    const int N = in_sizes[0] / (B * 3);        // 8192

    float*  curv2  = (float*)d_ws;                         // B*N*3 f32
    float*  moved  = curv2 + (size_t)B * N * 3;            // B*N*3 f32
    float4* xyzw   = (float4*)(moved + (size_t)B * N * 3); // 6*N float4
    int*    sidx   = (int*)(xyzw + (size_t)6 * N);         // 6*N int
    int*    bstart = sidx + (size_t)6 * N;                 // 6*(NB1+1) int

    hipMemsetAsync(d_out, 0, sizeof(float), stream);

    sort_kernel<<<6, SBLK, 0, stream>>>(src, tgt, flow, xyzw, sidx, bstart, N);

    // fused self-KNN curvatures: CPQ=16, QPB=16 -> 2*B*N/16 = 2048 blocks
    knn_kernel<10, 16, 0, 96><<<2 * B * (N / 16), BLOCK, 0, stream>>>(
        src, tgt, flow, xyzw, sidx, bstart, nullptr, nullptr, curv2, moved, N, 0.f);

    // interp + loss: B*N/16 = 1024 blocks
    knn_kernel<5, 16, 1, 64><<<B * (N / 16), BLOCK, 0, stream>>>(
        src, tgt, flow, xyzw, sidx, bstart, curv2, moved, out, nullptr, N, 1.0f / B);
}